// Round 1
// baseline (359.164 us; speedup 1.0000x reference)
//
#include <hip/hip_runtime.h>

#define N_AB  1024
#define NHALF 1025
#define NFULL 2049
#define HDIM  64
#define PLANE ((size_t)N_AB * NFULL)

__device__ __forceinline__ float fast_tanh(float x) {
    // tanh(x) = (e^{2x}-1)/(e^{2x}+1); clamp so exp never overflows.
    x = fminf(fmaxf(x, -9.0f), 9.0f);
    float e = __builtin_amdgcn_exp2f(x * 2.885390081777927f); // exp(2x) = 2^(2x*log2e)
    return (e - 1.0f) * __builtin_amdgcn_rcpf(e + 1.0f);
}

// Evaluate one MLP (network n, abscissa x) + its JVP, produce xp,yp,xpp,ypp.
__device__ __forceinline__ float4 mlp_point(
    float x,
    const float* __restrict__ w0n, const float* __restrict__ b0n,
    const float* __restrict__ w1n, const float* __restrict__ b1n,
    const float* __restrict__ w2n, const float* __restrict__ b2n)
{
    float h[HDIM], dh[HDIM];
    #pragma unroll
    for (int j = 0; j < HDIM; ++j) {
        float w  = w0n[j];                    // block-uniform -> s_load
        float hj = fast_tanh(fmaf(w, x, b0n[j]));
        h[j]  = hj;
        dh[j] = (1.0f - hj * hj) * w;         // tangent of layer 1 (dx = 1)
    }
    float z30 = b2n[0], z31 = b2n[1];
    float dz30 = 0.0f, dz31 = 0.0f;
    #pragma unroll 2
    for (int i = 0; i < HDIM; ++i) {
        float acc = b1n[i], dacc = 0.0f;
        const float* __restrict__ row = w1n + i * HDIM;
        #pragma unroll
        for (int j = 0; j < HDIM; ++j) {
            float w = row[j];                 // block-uniform -> s_load (SGPR operand)
            acc  = fmaf(w, h[j],  acc);
            dacc = fmaf(w, dh[j], dacc);
        }
        float h2  = fast_tanh(acc);
        float dh2 = (1.0f - h2 * h2) * dacc;
        float w20 = w2n[i], w21 = w2n[HDIM + i];
        z30  = fmaf(w20, h2,  z30);
        dz30 = fmaf(w20, dh2, dz30);
        z31  = fmaf(w21, h2,  z31);
        dz31 = fmaf(w21, dh2, dz31);
    }
    float a  = z30 * z30;
    float bb = z31 * z31;
    float da = 2.0f * z30 * dz30;
    float db = 2.0f * z31 * dz31;
    float sa = sinf(x), ca = cosf(x);
    float cam1 = ca - 1.0f;
    float4 r;
    r.x = a * cam1;                    // xp
    r.y = bb * sa;                     // yp
    r.z = fmaf(da, cam1, -(a * sa));   // xpp
    r.w = fmaf(bb, ca, db * sa);       // ypp
    return r;
}

__global__ __launch_bounds__(256, 2) void sofa_kernel(
    const float* __restrict__ alpha,
    const float* __restrict__ w0,
    const float* __restrict__ w1,
    const float* __restrict__ w2,
    const float* __restrict__ b0,
    const float* __restrict__ b1,
    const float* __restrict__ b2,
    float* __restrict__ out)
{
    const int n   = blockIdx.x;
    const int tid = threadIdx.x;

    const float* __restrict__ w0n = w0 + (size_t)n * HDIM;
    const float* __restrict__ b0n = b0 + (size_t)n * HDIM;
    const float* __restrict__ w1n = w1 + (size_t)n * HDIM * HDIM;
    const float* __restrict__ b1n = b1 + (size_t)n * HDIM;
    const float* __restrict__ w2n = w2 + (size_t)n * 2 * HDIM;
    const float* __restrict__ b2n = b2 + (size_t)n * 2;

    float* __restrict__ oxp  = out + (size_t)n * NFULL;
    float* __restrict__ oyp  = oxp + PLANE;
    float* __restrict__ oxpp = oxp + 2 * PLANE;
    float* __restrict__ oypp = oxp + 3 * PLANE;

    __shared__ float s_xplast;

    float rxp[4];

    // b = tid + 256k covers 0..1023 exactly (4*256 = 1024).
    #pragma unroll
    for (int k = 0; k < 4; ++k) {
        int b = tid + k * 256;
        float4 r = mlp_point(alpha[b], w0n, b0n, w1n, b1n, w2n, b2n);
        oxp[b]  = r.x;
        oyp[b]  = r.y;
        oxpp[b] = r.z;
        oypp[b] = r.w;
        int m = 2048 - b;            // mirror index, 1025..2048
        oyp[m]  = r.y;               // yp mirror:  +flip
        oxpp[m] = r.z;               // xpp mirror: +flip
        oypp[m] = -r.w;              // ypp mirror: -flip
        rxp[k] = r.x;
    }

    // b = 1024 (single odd point): one lane computes it; xp_last shared via LDS.
    if (tid == 0) {
        float4 r = mlp_point(alpha[NHALF - 1], w0n, b0n, w1n, b1n, w2n, b2n);
        oxp[NHALF - 1]  = r.x;
        oyp[NHALF - 1]  = r.y;
        oxpp[NHALF - 1] = r.z;
        oypp[NHALF - 1] = r.w;
        s_xplast = r.x;
    }
    __syncthreads();

    // xp mirror: xp[2048-b] = 2*xp_last - xp[b]
    float xl2 = 2.0f * s_xplast;
    #pragma unroll
    for (int k = 0; k < 4; ++k) {
        int b = tid + k * 256;
        oxp[2048 - b] = xl2 - rxp[k];
    }
}

extern "C" void kernel_launch(void* const* d_in, const int* in_sizes, int n_in,
                              void* d_out, int out_size, void* d_ws, size_t ws_size,
                              hipStream_t stream) {
    const float* alpha = (const float*)d_in[0];
    const float* w0    = (const float*)d_in[1];
    const float* w1    = (const float*)d_in[2];
    const float* w2    = (const float*)d_in[3];
    const float* b0    = (const float*)d_in[4];
    const float* b1    = (const float*)d_in[5];
    const float* b2    = (const float*)d_in[6];
    float* out = (float*)d_out;
    sofa_kernel<<<dim3(N_AB), dim3(256), 0, stream>>>(alpha, w0, w1, w2, b0, b1, b2, out);
}